// Round 10
// baseline (136.420 us; speedup 1.0000x reference)
//
#include <hip/hip_runtime.h>
#include <hip/hip_bf16.h>
#include <stdint.h>

// MLP: hidden = X @ W1^T + b1 ; out = hidden @ W2^T + b2
// X [16384,2048] f32, W1 [512,2048], b1 [512], W2 [2048,512], b2 [2048]
// R13: account gemm1_bf's 4500 cy/block-step against HW rates: per block-step
// LDS traffic = 96 KB (32 staged + 64 frag reads) -> 43 B/cy at 2 blocks/CU,
// while gemm2 (same structure, 5 blocks/CU) runs 91 B/cy = the m134 ds_read
// ceiling. gemm2 is LDS-BW-saturated; gemm1 starves the LDS for concurrency.
// R8's occupancy null was in the f32-X regime (rule #23) and doesn't apply.
// Fix (one variable): gemm1_bf tile 128x128 -> 64x128 bf16: LDS 24 KB ->
// 6 blocks/CU cap, grid 1024 -> 4 co-resident blocks/CU (16 waves), same
// 2-barrier loop / swizzles / staging map, acc[2][4], 2x2 waves of 32x64.
// cast pass and gemm2 unchanged (controls).

typedef short bf16x8 __attribute__((ext_vector_type(8)));
typedef float f32x4 __attribute__((ext_vector_type(4)));

static __device__ __forceinline__ unsigned short f32_to_bf16_rne(float f) {
    unsigned int u = __float_as_uint(f);
    u += 0x7fffu + ((u >> 16) & 1u);
    return (unsigned short)(u >> 16);
}

// one kernel casts X, W1, W2 (f32 -> bf16), grid-stride over float4s
__global__ void cast_bf16_all(const float* __restrict__ x,
                              unsigned short* __restrict__ xo, int nx4,
                              const float* __restrict__ w1,
                              unsigned short* __restrict__ w1o,
                              const float* __restrict__ w2,
                              unsigned short* __restrict__ w2o, int nw4) {
    const int total = nx4 + 2 * nw4;
    const int stride = gridDim.x * blockDim.x;
    for (int i = blockIdx.x * blockDim.x + threadIdx.x; i < total; i += stride) {
        const float* in;
        unsigned short* out;
        int j;
        if (i < nx4) {
            in = x; out = xo; j = i;
        } else if (i < nx4 + nw4) {
            in = w1; out = w1o; j = i - nx4;
        } else {
            in = w2; out = w2o; j = i - nx4 - nw4;
        }
        float4 v = ((const float4*)in)[j];
        ushort4 o;
        o.x = f32_to_bf16_rne(v.x);
        o.y = f32_to_bf16_rne(v.y);
        o.z = f32_to_bf16_rne(v.z);
        o.w = f32_to_bf16_rne(v.w);
        ((ushort4*)out)[j] = o;
    }
}

#define GLOAD_LDS16(gsrc, ldst)                                              \
    __builtin_amdgcn_global_load_lds(                                        \
        (const __attribute__((address_space(1))) void*)(gsrc),               \
        (__attribute__((address_space(3))) void*)(ldst), 16, 0, 0)

// ---------------------------------------------------------------------------
// GEMM1 (bf16): H[16384][512] bf16 = Xbf[16384][2048] @ W1bf[512][2048]^T + b1
// 64x128 tile, 256 thr (2x2 waves of 32x64), BK=64, single-buffered 24 KB
// -> 6 blocks/CU LDS-cap; grid = 256*4 = 1024 blocks -> 4 co-resident/CU.
// K=2048 -> NSTEP=32. gemm2's exact 2-barrier loop. Chunked XCD swizzle
// (q=128; the 4 col-panels sharing an A-panel adjacent -> same-XCD L2 dedupe).
// LDS rows 128 B = 8 x 16B units, phys_unit = logical ^ (row&7).
// ---------------------------------------------------------------------------
__global__ __launch_bounds__(256)
void gemm1_bf(const unsigned short* __restrict__ A,
              const unsigned short* __restrict__ Bt,
              const float* __restrict__ bias,
              unsigned short* __restrict__ H) {
    constexpr int N = 512, Kd = 2048, BK = 64, NSTEP = Kd / BK;  // 32 steps

    __shared__ __align__(16) unsigned short ldsA[64 * BK];   // 8 KB
    __shared__ __align__(16) unsigned short ldsB[128 * BK];  // 16 KB

    const int tid  = threadIdx.x;
    const int lane = tid & 63;
    const int wid  = tid >> 6;   // 0..3
    const int wr   = wid >> 1;   // 0..1 : 32-row half
    const int wc   = wid & 1;    // 0..1 : 64-col half

    const int bid = blockIdx.x;
    const int swz = ((bid & 7) << 7) + (bid >> 3);   // nwg=1024, q=128
    const int bm  = swz >> 2;            // 0..255 : 64-row panel
    const int bn  = swz & 3;             // 0..3   : 128-col panel
    const int brow = bm << 6;
    const int bcol = bn << 7;

    const int lrow = lane & 15;
    const int ku   = lane >> 4;
    const int rx   = lrow & 7;

    const int srow = tid >> 3;           // 0..31
    const int sgu  = (tid & 7) ^ (srow & 7);

    f32x4 acc[2][4] = {};

    auto stage = [&](int k0) {
#pragma unroll
        for (int i = 0; i < 2; ++i) {
            const int row = i * 32 + srow;
            const char* sa =
                (const char*)(A + (size_t)(brow + row) * Kd + k0) + (sgu << 4);
            GLOAD_LDS16(sa, (char*)ldsA + i * 4096 + tid * 16);
        }
#pragma unroll
        for (int i = 0; i < 4; ++i) {
            const int row = i * 32 + srow;
            const char* sb =
                (const char*)(Bt + (size_t)(bcol + row) * Kd + k0) + (sgu << 4);
            GLOAD_LDS16(sb, (char*)ldsB + i * 4096 + tid * 16);
        }
    };
    auto compute = [&]() {
#pragma unroll
        for (int kk = 0; kk < 2; ++kk) {
            const int un = ((ku + (kk << 2)) ^ rx) << 4;
            bf16x8 a[2], b[4];
#pragma unroll
            for (int m = 0; m < 2; ++m)
                a[m] = *(const bf16x8*)((const char*)ldsA +
                       ((wr << 5) + (m << 4) + lrow) * 128 + un);
#pragma unroll
            for (int n = 0; n < 4; ++n)
                b[n] = *(const bf16x8*)((const char*)ldsB +
                       ((wc << 6) + (n << 4) + lrow) * 128 + un);
#pragma unroll
            for (int m = 0; m < 2; ++m)
#pragma unroll
                for (int n = 0; n < 4; ++n)
                    acc[m][n] = __builtin_amdgcn_mfma_f32_16x16x32_bf16(
                        a[m], b[n], acc[m][n], 0, 0, 0);
        }
    };

    stage(0);
    __syncthreads();

#pragma unroll 1
    for (int t = 0; t < NSTEP; ++t) {
        compute();
        if (t + 1 < NSTEP) {
            __syncthreads();
            stage((t + 1) * BK);
            __syncthreads();
        }
    }

    // epilogue: C/D layout col = lane&15, row = (lane>>4)*4 + j  [m89]
    const int r0 = (lane >> 4) << 2;
#pragma unroll
    for (int n = 0; n < 4; ++n) {
        const int col = bcol + (wc << 6) + (n << 4) + lrow;
        const float bb = bias[col];
#pragma unroll
        for (int m = 0; m < 2; ++m)
#pragma unroll
            for (int j = 0; j < 4; ++j) {
                const int row = brow + (wr << 5) + (m << 4) + r0 + j;
                H[(size_t)row * N + col] = f32_to_bf16_rne(acc[m][n][j] + bb);
            }
    }
}

// ---------------------------------------------------------------------------
// GEMM2: out[16384][2048] f32 = Hbf[16384][512] @ W2bf[2048][512]^T + b2
// 128x128 tile, 256 thr, BK=64, single-buffered 32 KB -> 5 blocks/CU.
// grid = 128*16 = 2048 blocks, chunked XCD swizzle (q=256). (unchanged)
// ---------------------------------------------------------------------------
__global__ __launch_bounds__(256)
void gemm2(const unsigned short* __restrict__ A,
           const unsigned short* __restrict__ Bt,
           const float* __restrict__ bias,
           float* __restrict__ C) {
    constexpr int N = 2048, Kd = 512, BK = 64, NSTEP = Kd / BK;  // 8 steps

    __shared__ __align__(16) unsigned short ldsA[128 * BK];  // 16 KB
    __shared__ __align__(16) unsigned short ldsB[128 * BK];  // 16 KB

    const int tid  = threadIdx.x;
    const int lane = tid & 63;
    const int wid  = tid >> 6;
    const int wr   = wid >> 1;
    const int wc   = wid & 1;

    const int bid = blockIdx.x;
    const int swz = ((bid & 7) << 8) + (bid >> 3);   // nwg=2048, q=256
    const int bn  = swz & 15;
    const int bm  = swz >> 4;
    const int brow = bm << 7;
    const int bcol = bn << 7;

    const int lrow = lane & 15;
    const int ku   = lane >> 4;
    const int rx   = lrow & 7;

    const int srow = tid >> 3;
    const int sgu  = (tid & 7) ^ (srow & 7);

    f32x4 acc[4][4] = {};

    auto stage = [&](int k0) {
#pragma unroll
        for (int i = 0; i < 4; ++i) {
            const int row = i * 32 + srow;
            const char* sa =
                (const char*)(A + (size_t)(brow + row) * Kd + k0) + (sgu << 4);
            const char* sb =
                (const char*)(Bt + (size_t)(bcol + row) * Kd + k0) + (sgu << 4);
            GLOAD_LDS16(sa, (char*)ldsA + i * 4096 + tid * 16);
            GLOAD_LDS16(sb, (char*)ldsB + i * 4096 + tid * 16);
        }
    };
    auto compute = [&]() {
#pragma unroll
        for (int kk = 0; kk < 2; ++kk) {
            const int un = ((ku + (kk << 2)) ^ rx) << 4;
            bf16x8 a[4], b[4];
#pragma unroll
            for (int m = 0; m < 4; ++m)
                a[m] = *(const bf16x8*)((const char*)ldsA +
                       ((wr << 6) + (m << 4) + lrow) * 128 + un);
#pragma unroll
            for (int n = 0; n < 4; ++n)
                b[n] = *(const bf16x8*)((const char*)ldsB +
                       ((wc << 6) + (n << 4) + lrow) * 128 + un);
#pragma unroll
            for (int m = 0; m < 4; ++m)
#pragma unroll
                for (int n = 0; n < 4; ++n)
                    acc[m][n] = __builtin_amdgcn_mfma_f32_16x16x32_bf16(
                        a[m], b[n], acc[m][n], 0, 0, 0);
        }
    };

    stage(0);
    __syncthreads();

    for (int t = 0; t < NSTEP; ++t) {
        compute();
        if (t + 1 < NSTEP) {
            __syncthreads();
            stage((t + 1) * BK);
            __syncthreads();
        }
    }

    const int r0 = (lane >> 4) << 2;
#pragma unroll
    for (int n = 0; n < 4; ++n) {
        const int col = bcol + (wc << 6) + (n << 4) + lrow;
        const float bb = bias[col];
#pragma unroll
        for (int m = 0; m < 4; ++m)
#pragma unroll
            for (int j = 0; j < 4; ++j) {
                const int row = brow + (wr << 6) + (m << 4) + r0 + j;
                C[(size_t)row * N + col] = acc[m][n][j] + bb;
            }
    }
}

extern "C" void kernel_launch(void* const* d_in, const int* in_sizes, int n_in,
                              void* d_out, int out_size, void* d_ws, size_t ws_size,
                              hipStream_t stream) {
    const float* X  = (const float*)d_in[0];   // [16384][2048]
    const float* W1 = (const float*)d_in[1];   // [512][2048]
    const float* b1 = (const float*)d_in[2];   // [512]
    const float* W2 = (const float*)d_in[3];   // [2048][512]
    const float* b2 = (const float*)d_in[4];   // [2048]

    const int B = 16384, M = 2048, Kd = 512;

    // workspace: W1bf (2MB), W2bf (2MB), Hbf (16.8MB), Xbf (64MB)
    char* ws = (char*)d_ws;
    unsigned short* W1bf = (unsigned short*)ws;
    unsigned short* W2bf = W1bf + (size_t)Kd * M;
    unsigned short* Hbf  = W2bf + (size_t)M * Kd;
    unsigned short* Xbf  = Hbf + (size_t)B * Kd;

    const int nx4 = B * M / 4;        // 8,388,608 float4s
    const int nw4 = Kd * M / 4;       //   262,144 float4s each

    cast_bf16_all<<<4096, 256, 0, stream>>>(X, Xbf, nx4, W1, W1bf, W2, W2bf,
                                            nw4);

    gemm1_bf<<<(B / 64) * (Kd / 128), 256, 0, stream>>>(Xbf, W1bf, b1, Hbf);
    gemm2<<<(B / 128) * (M / 128), 256, 0, stream>>>(Hbf, W2bf, b2,
                                                     (float*)d_out);
}